// Round 6
// baseline (1691.706 us; speedup 1.0000x reference)
//
#include <hip/hip_runtime.h>
#include <float.h>
#include <stdint.h>

// DGCNN_Grouper forward on MI355X. B=8, N=2048, K=16, fp32.
// Round-2 validated architecture + round-3 validated FPS + one consolidated
// conv-pipeline kernel (megaC) using the round-3-validated full-grid barrier
// with co-residency GUARANTEED by __launch_bounds__(256,2) and grid=512.

#define DI __device__ __forceinline__
DI float f_add(float a, float b) { return __fadd_rn(a, b); }
DI float f_sub(float a, float b) { return __fsub_rn(a, b); }
DI float f_mul(float a, float b) { return __fmul_rn(a, b); }

DI uint64_t umax64(uint64_t a, uint64_t b) { return a > b ? a : b; }

// 6-step gfx9 DPP max-reduce over 64 lanes of a packed u64 key; broadcast via
// readlane 63. Identity 0 safe (real keys always nonzero). Validated r2/r3.
template<int CTRL, int RMASK>
DI uint64_t dpp_step_max(uint64_t k) {
  uint32_t lo = (uint32_t)__builtin_amdgcn_update_dpp(0, (int)(uint32_t)k,        CTRL, RMASK, 0xF, false);
  uint32_t hi = (uint32_t)__builtin_amdgcn_update_dpp(0, (int)(uint32_t)(k >> 32), CTRL, RMASK, 0xF, false);
  uint64_t o = ((uint64_t)hi << 32) | lo;
  return umax64(k, o);
}
DI uint64_t wave_max_bcast(uint64_t k) {
  k = dpp_step_max<0x111, 0xF>(k);  // row_shr:1
  k = dpp_step_max<0x112, 0xF>(k);  // row_shr:2
  k = dpp_step_max<0x114, 0xF>(k);  // row_shr:4
  k = dpp_step_max<0x118, 0xF>(k);  // row_shr:8
  k = dpp_step_max<0x142, 0xA>(k);  // row_bcast15
  k = dpp_step_max<0x143, 0xC>(k);  // row_bcast31
  uint32_t lo = (uint32_t)__builtin_amdgcn_readlane((int)(uint32_t)k, 63);
  uint32_t hi = (uint32_t)__builtin_amdgcn_readlane((int)(uint32_t)(k >> 32), 63);
  return ((uint64_t)hi << 32) | lo;
}

// Grid-wide barrier (validated round 3). Caller must guarantee co-residency.
DI void gbar(int* ctr, int target) {
  __threadfence();
  __syncthreads();
  if (threadIdx.x == 0) {
    __hip_atomic_fetch_add(ctr, 1, __ATOMIC_ACQ_REL, __HIP_MEMORY_SCOPE_AGENT);
    while (__hip_atomic_load(ctr, __ATOMIC_ACQUIRE, __HIP_MEMORY_SCOPE_AGENT) < target)
      __builtin_amdgcn_s_sleep(2);
  }
  __syncthreads();
  __threadfence();
}

// ---------------------------------------------------------------------------
// kNN (round-2 verbatim): 16 smallest d2, stable ties, exact reference math.
// ---------------------------------------------------------------------------
template<int NK>
DI void knn_body(const float* __restrict__ cq, int Nq,
                 const float* __restrict__ ck, int* __restrict__ out,
                 int b, int qbase, float* smem)
{
  constexpr int CPL = NK / 64;
  float* xs = smem;
  float* ys = smem + NK;
  float* zs = smem + 2*NK;
  float* rr = smem + 3*NK;
  const int tid = threadIdx.x;
  for (int i = tid; i < NK; i += 256) {
    float a  = ck[((size_t)b*3 + 0)*NK + i];
    float bb = ck[((size_t)b*3 + 1)*NK + i];
    float c  = ck[((size_t)b*3 + 2)*NK + i];
    xs[i] = a; ys[i] = bb; zs[i] = c;
    rr[i] = f_add(f_add(f_mul(a,a), f_mul(bb,bb)), f_mul(c,c));
  }
  __syncthreads();
  const int lane = tid & 63, w = tid >> 6;
  const int q = qbase + w;
  if (q >= Nq) return;
  float qx = cq[((size_t)b*3 + 0)*Nq + q];
  float qy = cq[((size_t)b*3 + 1)*Nq + q];
  float qz = cq[((size_t)b*3 + 2)*Nq + q];
  float qq = f_add(f_add(f_mul(qx,qx), f_mul(qy,qy)), f_mul(qz,qz));
  float v[CPL];
  #pragma unroll
  for (int j = 0; j < CPL; ++j) {
    int c = j*64 + lane;
    float dot = f_add(f_add(f_mul(qx,xs[c]), f_mul(qy,ys[c])), f_mul(qz,zs[c]));
    v[j] = f_sub(f_add(qq, rr[c]), f_mul(2.0f, dot));
  }
  unsigned mask = (CPL >= 32) ? 0xFFFFFFFFu : ((1u << CPL) - 1u);
  for (int r = 0; r < 16; ++r) {
    float bv = FLT_MAX; int bc = 0x7FFFFFFF;
    #pragma unroll
    for (int j = 0; j < CPL; ++j) {
      float vj = ((mask >> j) & 1u) ? v[j] : FLT_MAX;
      if (vj < bv) { bv = vj; bc = j*64 + lane; }
    }
    #pragma unroll
    for (int off = 32; off; off >>= 1) {
      float ov = __shfl_xor(bv, off);
      int   oc = __shfl_xor(bc, off);
      if (ov < bv || (ov == bv && oc < bc)) { bv = ov; bc = oc; }
    }
    if ((bc & 63) == lane) mask &= ~(1u << (bc >> 6));
    if (lane == 0) out[((size_t)b*16 + r)*Nq + q] = bc;
  }
}

// ---------------------------------------------------------------------------
// FPS (round-3 validated coord-carry): winner lane writes {key, coords} into
// per-wave LDS slot; next centroid via cndmask selects, no pts[far] read.
// ---------------------------------------------------------------------------
__device__ void fps_body(const float* __restrict__ x, int b,
                         int* __restrict__ s1, float* __restrict__ coorq,
                         int* __restrict__ s2, float* __restrict__ coorq2,
                         float* __restrict__ outc, char* smem_raw)
{
  float4*   pts  = (float4*)smem_raw;                       // [2048]
  int*      sel  = (int*)(smem_raw + 32768);                // [512]
  uint64_t* wkey = (uint64_t*)(smem_raw + 32768 + 2048);    // [8]
  float4*   wcrd = (float4*)(smem_raw + 32768 + 2048 + 64); // [8]
  const int tid = threadIdx.x, lane = tid & 63, w = tid >> 6;

  for (int i = tid; i < 2048; i += 256)
    pts[i] = make_float4(x[((size_t)b*3 + 0)*2048 + i],
                         x[((size_t)b*3 + 1)*2048 + i],
                         x[((size_t)b*3 + 2)*2048 + i], 0.f);
  __syncthreads();

  float px[8], py[8], pz[8], dl[8];
  #pragma unroll
  for (int j = 0; j < 8; ++j) {
    float4 p = pts[tid + 256*j];
    px[j] = p.x; py[j] = p.y; pz[j] = p.z; dl[j] = 1e10f;
  }

  __builtin_amdgcn_s_setprio(1);
  int far = 0;
  float4 c = pts[0];
  for (int i = 0; i < 512; ++i) {
    if (tid == 0) sel[i] = far;
    uint64_t k[8];
    #pragma unroll
    for (int j = 0; j < 8; ++j) {
      float dx = f_sub(px[j], c.x);
      float dy = f_sub(py[j], c.y);
      float dz = f_sub(pz[j], c.z);
      float d  = f_add(f_add(f_mul(dx,dx), f_mul(dy,dy)), f_mul(dz,dz));
      float nd = fminf(dl[j], d);
      dl[j] = nd;
      k[j] = ((uint64_t)__float_as_uint(nd) << 32) | (uint32_t)~(uint32_t)(tid + 256*j);
    }
    uint64_t a0 = umax64(k[0], k[1]), a1 = umax64(k[2], k[3]);
    uint64_t a2 = umax64(k[4], k[5]), a3 = umax64(k[6], k[7]);
    uint64_t kk = wave_max_bcast(umax64(umax64(a0, a1), umax64(a2, a3)));
    int slot = (i & 1)*4 + w;
    #pragma unroll
    for (int j = 0; j < 8; ++j)
      if (k[j] == kk) {   // keys unique: exactly one (lane,j) per wave
        wkey[slot] = kk;
        wcrd[slot] = make_float4(px[j], py[j], pz[j], 0.f);
      }
    __syncthreads();
    int sb = (i & 1)*4;
    uint64_t g0 = wkey[sb+0], g1 = wkey[sb+1], g2 = wkey[sb+2], g3 = wkey[sb+3];
    float4 c0 = wcrd[sb+0], c1 = wcrd[sb+1], c2 = wcrd[sb+2], c3 = wcrd[sb+3];
    uint64_t m01 = umax64(g0, g1), m23 = umax64(g2, g3);
    uint64_t gg  = umax64(m01, m23);
    float4 ca = (g0 >= g1) ? c0 : c1;
    float4 cb = (g2 >= g3) ? c2 : c3;
    c = (m01 >= m23) ? ca : cb;
    far = (int)~(uint32_t)gg;
  }
  __builtin_amdgcn_s_setprio(0);
  __syncthreads();

  // Dump level 1; bounce selected points into pts[0..511].
  int p0 = sel[tid], p1 = sel[tid + 256];
  float4 v0 = pts[p0], v1 = pts[p1];
  s1[b*512 + tid]       = p0;
  s1[b*512 + tid + 256] = p1;
  coorq[((size_t)b*3 + 0)*512 + tid] = v0.x;
  coorq[((size_t)b*3 + 1)*512 + tid] = v0.y;
  coorq[((size_t)b*3 + 2)*512 + tid] = v0.z;
  coorq[((size_t)b*3 + 0)*512 + tid + 256] = v1.x;
  coorq[((size_t)b*3 + 1)*512 + tid + 256] = v1.y;
  coorq[((size_t)b*3 + 2)*512 + tid + 256] = v1.z;
  __syncthreads();               // all pts reads complete before overwrite
  pts[tid] = v0; pts[tid + 256] = v1;
  __syncthreads();

  // Level 2: 512 -> 128, single wave, no barriers in loop (validated r2/r3).
  if (w == 0) {
    __builtin_amdgcn_s_setprio(1);
    float qx[8], qy[8], qz[8], d2[8];
    #pragma unroll
    for (int j = 0; j < 8; ++j) {
      float4 p = pts[lane + 64*j];
      qx[j] = p.x; qy[j] = p.y; qz[j] = p.z; d2[j] = 1e10f;
    }
    int far2 = 0;
    for (int i = 0; i < 128; ++i) {
      if (lane == 0) sel[i] = far2;
      float4 cc = pts[far2];
      uint64_t k[8];
      #pragma unroll
      for (int j = 0; j < 8; ++j) {
        float dx = f_sub(qx[j], cc.x);
        float dy = f_sub(qy[j], cc.y);
        float dz = f_sub(qz[j], cc.z);
        float d  = f_add(f_add(f_mul(dx,dx), f_mul(dy,dy)), f_mul(dz,dz));
        float nd = fminf(d2[j], d);
        d2[j] = nd;
        k[j] = ((uint64_t)__float_as_uint(nd) << 32) | (uint32_t)~(uint32_t)(lane + 64*j);
      }
      uint64_t a0 = umax64(k[0], k[1]), a1 = umax64(k[2], k[3]);
      uint64_t a2 = umax64(k[4], k[5]), a3 = umax64(k[6], k[7]);
      uint64_t kk = wave_max_bcast(umax64(umax64(a0, a1), umax64(a2, a3)));
      far2 = (int)~(uint32_t)kk;
    }
    __builtin_amdgcn_s_setprio(0);
  }
  __syncthreads();
  if (tid < 128) {
    int p = sel[tid];
    float4 v = pts[p];
    s2[b*128 + tid] = p;
    coorq2[((size_t)b*3 + 0)*128 + tid] = v.x;
    coorq2[((size_t)b*3 + 1)*128 + tid] = v.y;
    coorq2[((size_t)b*3 + 2)*128 + tid] = v.z;
    outc[((size_t)b*3 + 0)*128 + tid] = v.x;
    outc[((size_t)b*3 + 1)*128 + tid] = v.y;
    outc[((size_t)b*3 + 2)*128 + tid] = v.z;
  }
}

// ---------------------------------------------------------------------------
// mega1 (round-2 structure): blocks 0-7 FPS, 8-71 input_trans, 72+ knn1.
// ---------------------------------------------------------------------------
__global__ __launch_bounds__(256) void mega1(
    const float* __restrict__ x, const float* __restrict__ w_in, const float* __restrict__ b_in,
    float* __restrict__ f0T, int* __restrict__ idx1,
    int* __restrict__ s1, float* __restrict__ coorq,
    int* __restrict__ s2, float* __restrict__ coorq2, float* __restrict__ outc)
{
  __shared__ char smem_raw[35008] __attribute__((aligned(16)));
  const int bid = blockIdx.x;
  if (bid < 8) {
    fps_body(x, bid, s1, coorq, s2, coorq2, outc, smem_raw);
  } else if (bid < 72) {
    int t = (bid - 8)*256 + threadIdx.x;
    int b = t >> 11, n = t & 2047;
    float x0 = x[((size_t)b*3 + 0)*2048 + n];
    float x1 = x[((size_t)b*3 + 1)*2048 + n];
    float x2 = x[((size_t)b*3 + 2)*2048 + n];
    float* op = f0T + (size_t)t*8;
    #pragma unroll
    for (int o = 0; o < 8; ++o)
      op[o] = w_in[o*3+0]*x0 + w_in[o*3+1]*x1 + w_in[o*3+2]*x2 + b_in[o];
  } else {
    int vb = bid - 72;
    int b = vb >> 9;
    int qbase = (vb & 511)*4;
    knn_body<2048>(x, 2048, x, idx1, b, qbase, (float*)smem_raw);
  }
}

// ---------------------------------------------------------------------------
// Edge conv pass1 body (round-2 verbatim, round-2 ybuf indexing).
// ---------------------------------------------------------------------------
template<int C, int O, int NQ, int NK, bool STORE>
DI void conv_p1_body(
    const float* __restrict__ xqT, int xq_cols, const int* __restrict__ qg,
    const float* __restrict__ xkT, const int* __restrict__ knn_idx,
    const float* __restrict__ w, float* __restrict__ y, float* __restrict__ stats,
    int nt, int g, int b, float* smem)
{
  constexpr int GRP = O/4;
  const int tid = threadIdx.x;
  float* sxq = smem;
  float* sw  = smem + 16*C;
  float* red = sw + GRP*2*C;
  for (int i = tid; i < 16*C; i += 256) {
    int nn = i / C, ci = i % C;
    int q = nt*16 + nn;
    int src = qg ? qg[b*NQ + q] : q;
    sxq[i] = xqT[((size_t)b*xq_cols + src)*C + ci];
  }
  for (int i = tid; i < GRP*2*C; i += 256)
    sw[i] = w[(size_t)g*GRP*2*C + i];
  __syncthreads();

  const int nloc = tid >> 4, kk = tid & 15;
  const int n = nt*16 + nloc;
  const int flat = n*16 + kk;
  const int r = flat / NQ, s = flat % NQ;
  const int nbr = knn_idx[((size_t)b*16 + r)*NQ + s];

  float xqv[C], h1[C];
  {
    const float4* xq4 = (const float4*)(sxq + nloc*C);
    const float4* xk4 = (const float4*)(xkT + ((size_t)b*NK + nbr)*C);
    #pragma unroll
    for (int c4 = 0; c4 < C/4; ++c4) {
      float4 a = xq4[c4], k = xk4[c4];
      xqv[4*c4+0] = a.x; xqv[4*c4+1] = a.y; xqv[4*c4+2] = a.z; xqv[4*c4+3] = a.w;
      h1[4*c4+0] = k.x - a.x; h1[4*c4+1] = k.y - a.y;
      h1[4*c4+2] = k.z - a.z; h1[4*c4+3] = k.w - a.w;
    }
  }
  float lsum = 0.f, lsq = 0.f;
  float* yp = nullptr;
  if constexpr (STORE) yp = y + (((size_t)b*O + (size_t)g*GRP)*NQ + n)*16 + kk;
  for (int o = 0; o < GRP; ++o) {
    const float4* wr = (const float4*)(sw + o*2*C);
    float acc = 0.f;
    #pragma unroll
    for (int c4 = 0; c4 < C/4; ++c4) {
      float4 w4 = wr[c4];
      acc += w4.x*h1[4*c4] + w4.y*h1[4*c4+1] + w4.z*h1[4*c4+2] + w4.w*h1[4*c4+3];
    }
    #pragma unroll
    for (int c4 = 0; c4 < C/4; ++c4) {
      float4 w4 = wr[C/4 + c4];
      acc += w4.x*xqv[4*c4] + w4.y*xqv[4*c4+1] + w4.z*xqv[4*c4+2] + w4.w*xqv[4*c4+3];
    }
    if constexpr (STORE) yp[(size_t)o*NQ*16] = acc;
    lsum += acc; lsq += acc*acc;
  }
  #pragma unroll
  for (int off = 32; off; off >>= 1) {
    lsum += __shfl_xor(lsum, off);
    lsq  += __shfl_xor(lsq, off);
  }
  const int lane = tid & 63, wvid = tid >> 6;
  if (lane == 0) { red[wvid] = lsum; red[4+wvid] = lsq; }
  __syncthreads();
  if (tid == 0) {
    float s0  = (red[0]+red[1]) + (red[2]+red[3]);
    float s1v = (red[4]+red[5]) + (red[6]+red[7]);
    atomicAdd(stats + ((size_t)b*4 + g)*2,     s0);
    atomicAdd(stats + ((size_t)b*4 + g)*2 + 1, s1v);
  }
}

// pass2 (round-2 indexing): normalize + affine + lrelu + max over k.
template<int O, int NQ, bool TOUT>
DI void conv_p2_body(const float* __restrict__ y, const float* __restrict__ stats,
                     const float* __restrict__ gamma, const float* __restrict__ beta,
                     float* __restrict__ fout, int task)
{
  int t = task*256 + threadIdx.x;
  if (t < 8*O*NQ) {
    int b = t / (O*NQ);
    int rem = t % (O*NQ);
    int o, n;
    if (TOUT) { o = rem % O; n = rem / O; }
    else      { n = rem % NQ; o = rem / NQ; }
    int g = o / (O/4);
    const float cnt = (float)((O/4) * NQ * 16);
    float s0 = stats[((size_t)b*4 + g)*2], s1v = stats[((size_t)b*4 + g)*2 + 1];
    float mu = s0 / cnt;
    float var = fmaxf(s1v / cnt - mu*mu, 0.f);
    float rs = 1.f / sqrtf(var + 1e-5f);
    float ga = gamma[o], be = beta[o];
    const float4* yp = (const float4*)(y + ((((size_t)b*O + o)*NQ) + n)*16);
    float m = -FLT_MAX;
    #pragma unroll
    for (int i = 0; i < 4; ++i) {
      float4 v4 = yp[i];
      float vv[4] = {v4.x, v4.y, v4.z, v4.w};
      #pragma unroll
      for (int j = 0; j < 4; ++j) {
        float a = (vv[j] - mu)*rs*ga + be;
        a = a >= 0.f ? a : 0.2f*a;
        m = fmaxf(m, a);
      }
    }
    fout[t] = m;
  }
}

// Layer-1 pass2 body (round-2 verbatim).
DI void l1_pass2_body(const float* __restrict__ f0T, const int* __restrict__ idx1,
                      const float* __restrict__ w1, const float* __restrict__ stats,
                      const float* __restrict__ g1, const float* __restrict__ be1,
                      float* __restrict__ f1T, int blk, float* smem)
{
  float* sw = smem;
  float* sg = smem + 512;
  float* sb = smem + 544;
  int tid = threadIdx.x;
  for (int i = tid; i < 512; i += 256) sw[i] = w1[i];
  if (tid < 32) { sg[tid] = g1[tid]; sb[tid] = be1[tid]; }
  __syncthreads();
  int t = blk*256 + tid;
  int b = t >> 11, n = t & 2047;
  float mean[4], rstd[4];
  const float cnt = 8.f*2048.f*16.f;
  #pragma unroll
  for (int g = 0; g < 4; ++g) {
    float mu = stats[(b*4+g)*2] / cnt;
    float var = fmaxf(stats[(b*4+g)*2+1]/cnt - mu*mu, 0.f);
    mean[g] = mu; rstd[g] = 1.f/sqrtf(var + 1e-5f);
  }
  const float4* xqp = (const float4*)(f0T + (size_t)t*8);
  float4 q0 = xqp[0], q1 = xqp[1];
  float xq[8] = {q0.x,q0.y,q0.z,q0.w,q1.x,q1.y,q1.z,q1.w};
  float h[16][8];
  #pragma unroll
  for (int kk = 0; kk < 16; ++kk) {
    int flat = n*16 + kk, r = flat >> 11, s = flat & 2047;
    int nbr = idx1[((b*16 + r) << 11) + s];
    const float4* xkp = (const float4*)(f0T + ((size_t)(b << 11) + nbr)*8);
    float4 k0 = xkp[0], k1 = xkp[1];
    h[kk][0]=k0.x-xq[0]; h[kk][1]=k0.y-xq[1]; h[kk][2]=k0.z-xq[2]; h[kk][3]=k0.w-xq[3];
    h[kk][4]=k1.x-xq[4]; h[kk][5]=k1.y-xq[5]; h[kk][6]=k1.z-xq[6]; h[kk][7]=k1.w-xq[7];
  }
  float* op = f1T + (size_t)t*32;
  for (int o = 0; o < 32; ++o) {
    const float4* wp4 = (const float4*)(sw + o*16);
    float4 wa = wp4[0], wb = wp4[1], wc = wp4[2], wd = wp4[3];
    float base = wc.x*xq[0]+wc.y*xq[1]+wc.z*xq[2]+wc.w*xq[3]
               + wd.x*xq[4]+wd.y*xq[5]+wd.z*xq[6]+wd.w*xq[7];
    int g = o >> 3;
    float mu = mean[g], rs = rstd[g], ga = sg[o], be = sb[o];
    float m = -FLT_MAX;
    #pragma unroll
    for (int kk = 0; kk < 16; ++kk) {
      float acc = base
        + wa.x*h[kk][0]+wa.y*h[kk][1]+wa.z*h[kk][2]+wa.w*h[kk][3]
        + wb.x*h[kk][4]+wb.y*h[kk][5]+wb.z*h[kk][6]+wb.w*h[kk][7];
      float a2 = (acc - mu)*rs*ga + be;
      a2 = a2 >= 0.f ? a2 : 0.2f*a2;
      m = fmaxf(m, a2);
    }
    op[o] = m;
  }
}

// ---------------------------------------------------------------------------
// mega2 (round-2 verbatim): knn2 + L1 stats + knn3 + knn4. Grid 6400.
// ---------------------------------------------------------------------------
__global__ __launch_bounds__(256) void mega2(
    const float* __restrict__ f0T, const int* __restrict__ idx1,
    const float* __restrict__ w1, float* __restrict__ stats,
    const float* __restrict__ x, const float* __restrict__ coorq,
    const float* __restrict__ coorq2,
    int* __restrict__ idx2, int* __restrict__ idx3, int* __restrict__ idx4)
{
  __shared__ char smem_raw[32768] __attribute__((aligned(16)));
  const int bid = blockIdx.x;
  if (bid < 1024) {
    knn_body<2048>(coorq, 512, x, idx2, bid >> 7, (bid & 127)*4, (float*)smem_raw);
  } else if (bid < 5120) {
    int f = bid - 1024;
    conv_p1_body<8, 32, 2048, 2048, false>(f0T, 2048, nullptr, f0T, idx1, w1,
                                           nullptr, stats,
                                           f & 127, (f >> 7) & 3, f >> 9,
                                           (float*)smem_raw);
  } else if (bid < 6144) {
    int v = bid - 5120;
    knn_body<512>(coorq, 512, coorq, idx3, v >> 7, (v & 127)*4, (float*)smem_raw);
  } else {
    int v = bid - 6144;
    knn_body<512>(coorq2, 128, coorq, idx4, v >> 5, (v & 31)*4, (float*)smem_raw);
  }
}

// ---------------------------------------------------------------------------
// megaC: l1_pass2 + L2..L4 conv pipeline in ONE kernel. Grid 512.
// __launch_bounds__(256, 2) guarantees >=2 blocks/CU (VGPR<=256, LDS 20.5KB)
// -> all 512 blocks co-resident -> grid barrier deadlock-free.
// ---------------------------------------------------------------------------
__global__ __launch_bounds__(256, 2) void megaC(
    const float* __restrict__ f0T, const int* __restrict__ idx1,
    const float* __restrict__ w1, const float* __restrict__ g1, const float* __restrict__ be1,
    float* __restrict__ f1T,
    const int* __restrict__ s1, const int* __restrict__ idx2,
    const float* __restrict__ w2, const float* __restrict__ g2, const float* __restrict__ be2,
    float* __restrict__ f2T, const int* __restrict__ idx3,
    const float* __restrict__ w3, const float* __restrict__ g3, const float* __restrict__ be3,
    float* __restrict__ f3T, const int* __restrict__ s2g, const int* __restrict__ idx4,
    const float* __restrict__ w4, const float* __restrict__ g4, const float* __restrict__ be4,
    float* __restrict__ f4, float* __restrict__ stats, float* __restrict__ ybuf,
    int* flags)
{
  __shared__ float smem[5128] __attribute__((aligned(16)));
  const int bid = blockIdx.x;

  // Stage 0: l1_pass2 (64 tasks).
  if (bid < 64)
    l1_pass2_body(f0T, idx1, w1, stats, g1, be1, f1T, bid, smem);
  gbar(&flags[0], 512);

  // Stage 1: L2 p1 (C=32,O=64,Nq=512,Nk=2048): 1024 tasks, 2/block.
  #pragma unroll 1
  for (int t = bid*2; t < bid*2 + 2; ++t)
    conv_p1_body<32, 64, 512, 2048, true>(f1T, 2048, s1, f1T, idx2, w2, ybuf,
                                          stats + 64, t & 31, (t >> 5) & 3, t >> 7, smem);
  gbar(&flags[1], 512);

  // Stage 2: L2 p2 -> f2T [B,N,C]: 1024 tasks.
  for (int t = bid*2; t < bid*2 + 2; ++t)
    conv_p2_body<64, 512, true>(ybuf, stats + 64, g2, be2, f2T, t);
  gbar(&flags[2], 512);

  // Stage 3: L3 p1 (C=64,O=64,Nq=Nk=512): 1024 tasks.
  #pragma unroll 1
  for (int t = bid*2; t < bid*2 + 2; ++t)
    conv_p1_body<64, 64, 512, 512, true>(f2T, 512, nullptr, f2T, idx3, w3, ybuf,
                                         stats + 128, t & 31, (t >> 5) & 3, t >> 7, smem);
  gbar(&flags[3], 512);

  // Stage 4: L3 p2 -> f3T [B,N,C]: 1024 tasks.
  for (int t = bid*2; t < bid*2 + 2; ++t)
    conv_p2_body<64, 512, true>(ybuf, stats + 128, g3, be3, f3T, t);
  gbar(&flags[4], 512);

  // Stage 5: L4 p1 (C=64,O=128,Nq=128,Nk=512): 256 tasks.
  if (bid < 256)
    conv_p1_body<64, 128, 128, 512, true>(f3T, 512, s2g, f3T, idx4, w4, ybuf,
                                          stats + 192, bid & 7, (bid >> 3) & 3, bid >> 5, smem);
  gbar(&flags[5], 512);

  // Stage 6: L4 p2 -> f4 [B,O,NQ]: 512 tasks.
  conv_p2_body<128, 128, false>(ybuf, stats + 192, g4, be4, f4, bid);
}

// ---------------------------------------------------------------------------
extern "C" void kernel_launch(void* const* d_in, const int* in_sizes, int n_in,
                              void* d_out, int out_size, void* d_ws, size_t ws_size,
                              hipStream_t stream)
{
  (void)in_sizes; (void)n_in; (void)out_size; (void)ws_size;
  const float* x    = (const float*)d_in[0];
  const float* w_in = (const float*)d_in[1];
  const float* b_in = (const float*)d_in[2];
  const float* w1   = (const float*)d_in[3];
  const float* g1   = (const float*)d_in[4];
  const float* be1  = (const float*)d_in[5];
  const float* w2   = (const float*)d_in[6];
  const float* g2   = (const float*)d_in[7];
  const float* be2  = (const float*)d_in[8];
  const float* w3   = (const float*)d_in[9];
  const float* g3   = (const float*)d_in[10];
  const float* be3  = (const float*)d_in[11];
  const float* w4   = (const float*)d_in[12];
  const float* g4   = (const float*)d_in[13];
  const float* be4  = (const float*)d_in[14];

  float* ws = (float*)d_ws;
  float* stats  = ws;                      // 256 floats
  int*   flags  = (int*)(ws + 256);        // 64 ints (6 barrier counters used)
  float* f0T    = ws + 1536;               // [8,2048,8]   -> 132608
  int*   idx1   = (int*)(ws + 132608);     // [8,16,2048]  -> 394752
  float* f1T    = ws + 394752;             // [8,2048,32]  -> 919040
  int*   s1     = (int*)(ws + 919040);     // [8,512]      -> 923136
  float* coorq  = ws + 923136;             // [8,3,512]    -> 935424
  int*   idx2   = (int*)(ws + 935424);     // [8,16,512]   -> 1000960
  float* f2T    = ws + 1000960;            // [8,512,64]   -> 1263104
  int*   idx3   = (int*)(ws + 1263104);    // [8,16,512]   -> 1328640
  float* f3T    = ws + 1328640;            // [8,512,64]   -> 1590784
  int*   s2     = (int*)(ws + 1590784);    // [8,128]      -> 1591808
  float* coorq2 = ws + 1591808;            // [8,3,128]    -> 1594880
  int*   idx4   = (int*)(ws + 1594880);    // [8,16,128]   -> 1611264
  float* ybuf   = ws + 1611264;            // [8,64,512,16] max

  float* outc = (float*)d_out;             // [8,3,128]
  float* f4   = (float*)d_out + 3072;      // [8,128,128]

  hipMemsetAsync(d_ws, 0, 6144, stream);   // stats + flags

  // FPS(1+2) + input_trans + knn1.
  mega1<<<dim3(4168), 256, 0, stream>>>(
      x, w_in, b_in, f0T, idx1, s1, coorq, s2, coorq2, outc);

  // knn2 + L1 stats + knn3 + knn4.
  mega2<<<dim3(6400), 256, 0, stream>>>(
      f0T, idx1, w1, stats, x, coorq, coorq2, idx2, idx3, idx4);

  // l1_pass2 + L2..L4 pipeline (grid-barriered, co-residency guaranteed).
  megaC<<<dim3(512), 256, 0, stream>>>(
      f0T, idx1, w1, g1, be1, f1T, s1, idx2, w2, g2, be2, f2T, idx3,
      w3, g3, be3, f3T, s2, idx4, w4, g4, be4, f4, stats, ybuf, flags);
}

// Round 7
// 667.314 us; speedup vs baseline: 2.5351x; 2.5351x over previous
//
#include <hip/hip_runtime.h>
#include <float.h>
#include <stdint.h>

// DGCNN_Grouper forward on MI355X. B=8, N=2048, K=16, fp32.
// Round-2 proven architecture (stream-ordered dispatches, NO device-scope
// sync) + round-3/6 validated coord-carry FPS. 9 dispatches total.

#define DI __device__ __forceinline__
DI float f_add(float a, float b) { return __fadd_rn(a, b); }
DI float f_sub(float a, float b) { return __fsub_rn(a, b); }
DI float f_mul(float a, float b) { return __fmul_rn(a, b); }

DI uint64_t umax64(uint64_t a, uint64_t b) { return a > b ? a : b; }

// 6-step gfx9 DPP max-reduce over 64 lanes of a packed u64 key; broadcast via
// readlane 63. Identity 0 safe (real keys always nonzero). Validated r2/r3/r6.
template<int CTRL, int RMASK>
DI uint64_t dpp_step_max(uint64_t k) {
  uint32_t lo = (uint32_t)__builtin_amdgcn_update_dpp(0, (int)(uint32_t)k,        CTRL, RMASK, 0xF, false);
  uint32_t hi = (uint32_t)__builtin_amdgcn_update_dpp(0, (int)(uint32_t)(k >> 32), CTRL, RMASK, 0xF, false);
  uint64_t o = ((uint64_t)hi << 32) | lo;
  return umax64(k, o);
}
DI uint64_t wave_max_bcast(uint64_t k) {
  k = dpp_step_max<0x111, 0xF>(k);  // row_shr:1
  k = dpp_step_max<0x112, 0xF>(k);  // row_shr:2
  k = dpp_step_max<0x114, 0xF>(k);  // row_shr:4
  k = dpp_step_max<0x118, 0xF>(k);  // row_shr:8
  k = dpp_step_max<0x142, 0xA>(k);  // row_bcast15
  k = dpp_step_max<0x143, 0xC>(k);  // row_bcast31
  uint32_t lo = (uint32_t)__builtin_amdgcn_readlane((int)(uint32_t)k, 63);
  uint32_t hi = (uint32_t)__builtin_amdgcn_readlane((int)(uint32_t)(k >> 32), 63);
  return ((uint64_t)hi << 32) | lo;
}

// ---------------------------------------------------------------------------
// kNN (round-2 verbatim): 16 smallest d2, stable ties, exact reference math.
// ---------------------------------------------------------------------------
template<int NK>
DI void knn_body(const float* __restrict__ cq, int Nq,
                 const float* __restrict__ ck, int* __restrict__ out,
                 int b, int qbase, float* smem)
{
  constexpr int CPL = NK / 64;
  float* xs = smem;
  float* ys = smem + NK;
  float* zs = smem + 2*NK;
  float* rr = smem + 3*NK;
  const int tid = threadIdx.x;
  for (int i = tid; i < NK; i += 256) {
    float a  = ck[((size_t)b*3 + 0)*NK + i];
    float bb = ck[((size_t)b*3 + 1)*NK + i];
    float c  = ck[((size_t)b*3 + 2)*NK + i];
    xs[i] = a; ys[i] = bb; zs[i] = c;
    rr[i] = f_add(f_add(f_mul(a,a), f_mul(bb,bb)), f_mul(c,c));
  }
  __syncthreads();
  const int lane = tid & 63, w = tid >> 6;
  const int q = qbase + w;
  if (q >= Nq) return;
  float qx = cq[((size_t)b*3 + 0)*Nq + q];
  float qy = cq[((size_t)b*3 + 1)*Nq + q];
  float qz = cq[((size_t)b*3 + 2)*Nq + q];
  float qq = f_add(f_add(f_mul(qx,qx), f_mul(qy,qy)), f_mul(qz,qz));
  float v[CPL];
  #pragma unroll
  for (int j = 0; j < CPL; ++j) {
    int c = j*64 + lane;
    float dot = f_add(f_add(f_mul(qx,xs[c]), f_mul(qy,ys[c])), f_mul(qz,zs[c]));
    v[j] = f_sub(f_add(qq, rr[c]), f_mul(2.0f, dot));
  }
  unsigned mask = (CPL >= 32) ? 0xFFFFFFFFu : ((1u << CPL) - 1u);
  for (int r = 0; r < 16; ++r) {
    float bv = FLT_MAX; int bc = 0x7FFFFFFF;
    #pragma unroll
    for (int j = 0; j < CPL; ++j) {
      float vj = ((mask >> j) & 1u) ? v[j] : FLT_MAX;
      if (vj < bv) { bv = vj; bc = j*64 + lane; }
    }
    #pragma unroll
    for (int off = 32; off; off >>= 1) {
      float ov = __shfl_xor(bv, off);
      int   oc = __shfl_xor(bc, off);
      if (ov < bv || (ov == bv && oc < bc)) { bv = ov; bc = oc; }
    }
    if ((bc & 63) == lane) mask &= ~(1u << (bc >> 6));
    if (lane == 0) out[((size_t)b*16 + r)*Nq + q] = bc;
  }
}

// ---------------------------------------------------------------------------
// FPS (coord-carry, validated r3/r6): winner lane writes {key, coords} into
// per-wave LDS slot; next centroid via cndmask selects, no pts[far] read.
// ---------------------------------------------------------------------------
__device__ void fps_body(const float* __restrict__ x, int b,
                         int* __restrict__ s1, float* __restrict__ coorq,
                         int* __restrict__ s2, float* __restrict__ coorq2,
                         float* __restrict__ outc, char* smem_raw)
{
  float4*   pts  = (float4*)smem_raw;                       // [2048]
  int*      sel  = (int*)(smem_raw + 32768);                // [512]
  uint64_t* wkey = (uint64_t*)(smem_raw + 32768 + 2048);    // [8]
  float4*   wcrd = (float4*)(smem_raw + 32768 + 2048 + 64); // [8]
  const int tid = threadIdx.x, lane = tid & 63, w = tid >> 6;

  for (int i = tid; i < 2048; i += 256)
    pts[i] = make_float4(x[((size_t)b*3 + 0)*2048 + i],
                         x[((size_t)b*3 + 1)*2048 + i],
                         x[((size_t)b*3 + 2)*2048 + i], 0.f);
  __syncthreads();

  float px[8], py[8], pz[8], dl[8];
  #pragma unroll
  for (int j = 0; j < 8; ++j) {
    float4 p = pts[tid + 256*j];
    px[j] = p.x; py[j] = p.y; pz[j] = p.z; dl[j] = 1e10f;
  }

  __builtin_amdgcn_s_setprio(1);
  int far = 0;
  float4 c = pts[0];
  for (int i = 0; i < 512; ++i) {
    if (tid == 0) sel[i] = far;
    uint64_t k[8];
    #pragma unroll
    for (int j = 0; j < 8; ++j) {
      float dx = f_sub(px[j], c.x);
      float dy = f_sub(py[j], c.y);
      float dz = f_sub(pz[j], c.z);
      float d  = f_add(f_add(f_mul(dx,dx), f_mul(dy,dy)), f_mul(dz,dz));
      float nd = fminf(dl[j], d);
      dl[j] = nd;
      k[j] = ((uint64_t)__float_as_uint(nd) << 32) | (uint32_t)~(uint32_t)(tid + 256*j);
    }
    uint64_t a0 = umax64(k[0], k[1]), a1 = umax64(k[2], k[3]);
    uint64_t a2 = umax64(k[4], k[5]), a3 = umax64(k[6], k[7]);
    uint64_t kk = wave_max_bcast(umax64(umax64(a0, a1), umax64(a2, a3)));
    int slot = (i & 1)*4 + w;
    #pragma unroll
    for (int j = 0; j < 8; ++j)
      if (k[j] == kk) {   // keys unique: exactly one (lane,j) per wave
        wkey[slot] = kk;
        wcrd[slot] = make_float4(px[j], py[j], pz[j], 0.f);
      }
    __syncthreads();
    int sb = (i & 1)*4;
    uint64_t g0 = wkey[sb+0], g1 = wkey[sb+1], g2 = wkey[sb+2], g3 = wkey[sb+3];
    float4 c0 = wcrd[sb+0], c1 = wcrd[sb+1], c2 = wcrd[sb+2], c3 = wcrd[sb+3];
    uint64_t m01 = umax64(g0, g1), m23 = umax64(g2, g3);
    uint64_t gg  = umax64(m01, m23);
    float4 ca = (g0 >= g1) ? c0 : c1;
    float4 cb = (g2 >= g3) ? c2 : c3;
    c = (m01 >= m23) ? ca : cb;
    far = (int)~(uint32_t)gg;
  }
  __builtin_amdgcn_s_setprio(0);
  __syncthreads();

  // Dump level 1; bounce selected points into pts[0..511].
  int p0 = sel[tid], p1 = sel[tid + 256];
  float4 v0 = pts[p0], v1 = pts[p1];
  s1[b*512 + tid]       = p0;
  s1[b*512 + tid + 256] = p1;
  coorq[((size_t)b*3 + 0)*512 + tid] = v0.x;
  coorq[((size_t)b*3 + 1)*512 + tid] = v0.y;
  coorq[((size_t)b*3 + 2)*512 + tid] = v0.z;
  coorq[((size_t)b*3 + 0)*512 + tid + 256] = v1.x;
  coorq[((size_t)b*3 + 1)*512 + tid + 256] = v1.y;
  coorq[((size_t)b*3 + 2)*512 + tid + 256] = v1.z;
  __syncthreads();               // all pts reads complete before overwrite
  pts[tid] = v0; pts[tid + 256] = v1;
  __syncthreads();

  // Level 2: 512 -> 128, single wave, no barriers in loop (validated).
  if (w == 0) {
    __builtin_amdgcn_s_setprio(1);
    float qx[8], qy[8], qz[8], d2[8];
    #pragma unroll
    for (int j = 0; j < 8; ++j) {
      float4 p = pts[lane + 64*j];
      qx[j] = p.x; qy[j] = p.y; qz[j] = p.z; d2[j] = 1e10f;
    }
    int far2 = 0;
    for (int i = 0; i < 128; ++i) {
      if (lane == 0) sel[i] = far2;
      float4 cc = pts[far2];
      uint64_t k[8];
      #pragma unroll
      for (int j = 0; j < 8; ++j) {
        float dx = f_sub(qx[j], cc.x);
        float dy = f_sub(qy[j], cc.y);
        float dz = f_sub(qz[j], cc.z);
        float d  = f_add(f_add(f_mul(dx,dx), f_mul(dy,dy)), f_mul(dz,dz));
        float nd = fminf(d2[j], d);
        d2[j] = nd;
        k[j] = ((uint64_t)__float_as_uint(nd) << 32) | (uint32_t)~(uint32_t)(lane + 64*j);
      }
      uint64_t a0 = umax64(k[0], k[1]), a1 = umax64(k[2], k[3]);
      uint64_t a2 = umax64(k[4], k[5]), a3 = umax64(k[6], k[7]);
      uint64_t kk = wave_max_bcast(umax64(umax64(a0, a1), umax64(a2, a3)));
      far2 = (int)~(uint32_t)kk;
    }
    __builtin_amdgcn_s_setprio(0);
  }
  __syncthreads();
  if (tid < 128) {
    int p = sel[tid];
    float4 v = pts[p];
    s2[b*128 + tid] = p;
    coorq2[((size_t)b*3 + 0)*128 + tid] = v.x;
    coorq2[((size_t)b*3 + 1)*128 + tid] = v.y;
    coorq2[((size_t)b*3 + 2)*128 + tid] = v.z;
    outc[((size_t)b*3 + 0)*128 + tid] = v.x;
    outc[((size_t)b*3 + 1)*128 + tid] = v.y;
    outc[((size_t)b*3 + 2)*128 + tid] = v.z;
  }
}

// ---------------------------------------------------------------------------
// mega1: blocks 0-7 FPS, 8-71 input_trans, 72+ knn1. Mutually independent.
// ---------------------------------------------------------------------------
__global__ __launch_bounds__(256) void mega1(
    const float* __restrict__ x, const float* __restrict__ w_in, const float* __restrict__ b_in,
    float* __restrict__ f0T, int* __restrict__ idx1,
    int* __restrict__ s1, float* __restrict__ coorq,
    int* __restrict__ s2, float* __restrict__ coorq2, float* __restrict__ outc)
{
  __shared__ char smem_raw[35008] __attribute__((aligned(16)));
  const int bid = blockIdx.x;
  if (bid < 8) {
    fps_body(x, bid, s1, coorq, s2, coorq2, outc, smem_raw);
  } else if (bid < 72) {
    int t = (bid - 8)*256 + threadIdx.x;
    int b = t >> 11, n = t & 2047;
    float x0 = x[((size_t)b*3 + 0)*2048 + n];
    float x1 = x[((size_t)b*3 + 1)*2048 + n];
    float x2 = x[((size_t)b*3 + 2)*2048 + n];
    float* op = f0T + (size_t)t*8;
    #pragma unroll
    for (int o = 0; o < 8; ++o)
      op[o] = w_in[o*3+0]*x0 + w_in[o*3+1]*x1 + w_in[o*3+2]*x2 + b_in[o];
  } else {
    int vb = bid - 72;
    int b = vb >> 9;
    int qbase = (vb & 511)*4;
    knn_body<2048>(x, 2048, x, idx1, b, qbase, (float*)smem_raw);
  }
}

// ---------------------------------------------------------------------------
// Edge conv pass1 body (round-2 verbatim).
// ---------------------------------------------------------------------------
template<int C, int O, int NQ, int NK, bool STORE>
DI void conv_p1_body(
    const float* __restrict__ xqT, int xq_cols, const int* __restrict__ qg,
    const float* __restrict__ xkT, const int* __restrict__ knn_idx,
    const float* __restrict__ w, float* __restrict__ y, float* __restrict__ stats,
    int nt, int g, int b, float* smem)
{
  constexpr int GRP = O/4;
  const int tid = threadIdx.x;
  float* sxq = smem;
  float* sw  = smem + 16*C;
  float* red = sw + GRP*2*C;
  for (int i = tid; i < 16*C; i += 256) {
    int nn = i / C, ci = i % C;
    int q = nt*16 + nn;
    int src = qg ? qg[b*NQ + q] : q;
    sxq[i] = xqT[((size_t)b*xq_cols + src)*C + ci];
  }
  for (int i = tid; i < GRP*2*C; i += 256)
    sw[i] = w[(size_t)g*GRP*2*C + i];
  __syncthreads();

  const int nloc = tid >> 4, kk = tid & 15;
  const int n = nt*16 + nloc;
  const int flat = n*16 + kk;
  const int r = flat / NQ, s = flat % NQ;
  const int nbr = knn_idx[((size_t)b*16 + r)*NQ + s];

  float xqv[C], h1[C];
  {
    const float4* xq4 = (const float4*)(sxq + nloc*C);
    const float4* xk4 = (const float4*)(xkT + ((size_t)b*NK + nbr)*C);
    #pragma unroll
    for (int c4 = 0; c4 < C/4; ++c4) {
      float4 a = xq4[c4], k = xk4[c4];
      xqv[4*c4+0] = a.x; xqv[4*c4+1] = a.y; xqv[4*c4+2] = a.z; xqv[4*c4+3] = a.w;
      h1[4*c4+0] = k.x - a.x; h1[4*c4+1] = k.y - a.y;
      h1[4*c4+2] = k.z - a.z; h1[4*c4+3] = k.w - a.w;
    }
  }
  float lsum = 0.f, lsq = 0.f;
  float* yp = nullptr;
  if constexpr (STORE) yp = y + (((size_t)b*O + (size_t)g*GRP)*NQ + n)*16 + kk;
  for (int o = 0; o < GRP; ++o) {
    const float4* wr = (const float4*)(sw + o*2*C);
    float acc = 0.f;
    #pragma unroll
    for (int c4 = 0; c4 < C/4; ++c4) {
      float4 w4 = wr[c4];
      acc += w4.x*h1[4*c4] + w4.y*h1[4*c4+1] + w4.z*h1[4*c4+2] + w4.w*h1[4*c4+3];
    }
    #pragma unroll
    for (int c4 = 0; c4 < C/4; ++c4) {
      float4 w4 = wr[C/4 + c4];
      acc += w4.x*xqv[4*c4] + w4.y*xqv[4*c4+1] + w4.z*xqv[4*c4+2] + w4.w*xqv[4*c4+3];
    }
    if constexpr (STORE) yp[(size_t)o*NQ*16] = acc;
    lsum += acc; lsq += acc*acc;
  }
  #pragma unroll
  for (int off = 32; off; off >>= 1) {
    lsum += __shfl_xor(lsum, off);
    lsq  += __shfl_xor(lsq, off);
  }
  const int lane = tid & 63, wvid = tid >> 6;
  if (lane == 0) { red[wvid] = lsum; red[4+wvid] = lsq; }
  __syncthreads();
  if (tid == 0) {
    float s0  = (red[0]+red[1]) + (red[2]+red[3]);
    float s1v = (red[4]+red[5]) + (red[6]+red[7]);
    atomicAdd(stats + ((size_t)b*4 + g)*2,     s0);
    atomicAdd(stats + ((size_t)b*4 + g)*2 + 1, s1v);
  }
}

template<int C, int O, int NQ, int NK, bool STORE>
__global__ __launch_bounds__(256) void conv_p1(
    const float* __restrict__ xqT, int xq_cols, const int* __restrict__ qg,
    const float* __restrict__ xkT, const int* __restrict__ knn_idx,
    const float* __restrict__ w, float* __restrict__ y, float* __restrict__ stats)
{
  __shared__ float smem_f[16*C + (O/4)*2*C + 8];
  conv_p1_body<C, O, NQ, NK, STORE>(xqT, xq_cols, qg, xkT, knn_idx, w, y, stats,
                                    blockIdx.x, blockIdx.y, blockIdx.z, smem_f);
}

// ---------------------------------------------------------------------------
// mega2: knn2 + conv_p1(L1 stats) + knn3 + knn4 in one dispatch.
// ---------------------------------------------------------------------------
__global__ __launch_bounds__(256) void mega2(
    const float* __restrict__ f0T, const int* __restrict__ idx1,
    const float* __restrict__ w1, float* __restrict__ stats,
    const float* __restrict__ x, const float* __restrict__ coorq,
    const float* __restrict__ coorq2,
    int* __restrict__ idx2, int* __restrict__ idx3, int* __restrict__ idx4)
{
  __shared__ char smem_raw[32768] __attribute__((aligned(16)));
  const int bid = blockIdx.x;
  if (bid < 1024) {
    knn_body<2048>(coorq, 512, x, idx2, bid >> 7, (bid & 127)*4, (float*)smem_raw);
  } else if (bid < 5120) {
    int f = bid - 1024;
    conv_p1_body<8, 32, 2048, 2048, false>(f0T, 2048, nullptr, f0T, idx1, w1,
                                           nullptr, stats,
                                           f & 127, (f >> 7) & 3, f >> 9,
                                           (float*)smem_raw);
  } else if (bid < 6144) {
    int v = bid - 5120;
    knn_body<512>(coorq, 512, coorq, idx3, v >> 7, (v & 127)*4, (float*)smem_raw);
  } else {
    int v = bid - 6144;
    knn_body<512>(coorq2, 128, coorq, idx4, v >> 5, (v & 31)*4, (float*)smem_raw);
  }
}

// pass2 for layers 2-4.
template<int O, int NQ, bool TOUT>
__global__ __launch_bounds__(256) void conv_p2(
    const float* __restrict__ y, const float* __restrict__ stats,
    const float* __restrict__ gamma, const float* __restrict__ beta,
    float* __restrict__ fout)
{
  int t = blockIdx.x*256 + threadIdx.x;
  if (t >= 8*O*NQ) return;
  int b = t / (O*NQ);
  int rem = t % (O*NQ);
  int o, n;
  if (TOUT) { o = rem % O; n = rem / O; }
  else      { n = rem % NQ; o = rem / NQ; }
  int g = o / (O/4);
  const float cnt = (float)((O/4) * NQ * 16);
  float s0 = stats[((size_t)b*4 + g)*2], s1v = stats[((size_t)b*4 + g)*2 + 1];
  float mu = s0 / cnt;
  float var = fmaxf(s1v / cnt - mu*mu, 0.f);
  float rs = 1.f / sqrtf(var + 1e-5f);
  float ga = gamma[o], be = beta[o];
  const float4* yp = (const float4*)(y + ((((size_t)b*O + o)*NQ) + n)*16);
  float m = -FLT_MAX;
  #pragma unroll
  for (int i = 0; i < 4; ++i) {
    float4 v4 = yp[i];
    float vv[4] = {v4.x, v4.y, v4.z, v4.w};
    #pragma unroll
    for (int j = 0; j < 4; ++j) {
      float a = (vv[j] - mu)*rs*ga + be;
      a = a >= 0.f ? a : 0.2f*a;
      m = fmaxf(m, a);
    }
  }
  fout[t] = m;
}

// Layer-1 pass2: recompute conv + GN + lrelu + max.
__global__ __launch_bounds__(256) void l1_pass2(
    const float* __restrict__ f0T, const int* __restrict__ idx1,
    const float* __restrict__ w1, const float* __restrict__ stats,
    const float* __restrict__ g1, const float* __restrict__ be1,
    float* __restrict__ f1T)
{
  alignas(16) __shared__ float sw[512];
  __shared__ float sg[32], sb[32];
  int tid = threadIdx.x;
  for (int i = tid; i < 512; i += 256) sw[i] = w1[i];
  if (tid < 32) { sg[tid] = g1[tid]; sb[tid] = be1[tid]; }
  __syncthreads();
  int t = blockIdx.x*256 + tid;
  int b = t >> 11, n = t & 2047;
  float mean[4], rstd[4];
  const float cnt = 8.f*2048.f*16.f;
  #pragma unroll
  for (int g = 0; g < 4; ++g) {
    float mu = stats[(b*4+g)*2] / cnt;
    float var = fmaxf(stats[(b*4+g)*2+1]/cnt - mu*mu, 0.f);
    mean[g] = mu; rstd[g] = 1.f/sqrtf(var + 1e-5f);
  }
  const float4* xqp = (const float4*)(f0T + (size_t)t*8);
  float4 q0 = xqp[0], q1 = xqp[1];
  float xq[8] = {q0.x,q0.y,q0.z,q0.w,q1.x,q1.y,q1.z,q1.w};
  float h[16][8];
  #pragma unroll
  for (int kk = 0; kk < 16; ++kk) {
    int flat = n*16 + kk, r = flat >> 11, s = flat & 2047;
    int nbr = idx1[((b*16 + r) << 11) + s];
    const float4* xkp = (const float4*)(f0T + ((size_t)(b << 11) + nbr)*8);
    float4 k0 = xkp[0], k1 = xkp[1];
    h[kk][0]=k0.x-xq[0]; h[kk][1]=k0.y-xq[1]; h[kk][2]=k0.z-xq[2]; h[kk][3]=k0.w-xq[3];
    h[kk][4]=k1.x-xq[4]; h[kk][5]=k1.y-xq[5]; h[kk][6]=k1.z-xq[6]; h[kk][7]=k1.w-xq[7];
  }
  float* op = f1T + (size_t)t*32;
  for (int o = 0; o < 32; ++o) {
    const float4* wp4 = (const float4*)(sw + o*16);
    float4 wa = wp4[0], wb = wp4[1], wc = wp4[2], wd = wp4[3];
    float base = wc.x*xq[0]+wc.y*xq[1]+wc.z*xq[2]+wc.w*xq[3]
               + wd.x*xq[4]+wd.y*xq[5]+wd.z*xq[6]+wd.w*xq[7];
    int g = o >> 3;
    float mu = mean[g], rs = rstd[g], ga = sg[o], be = sb[o];
    float m = -FLT_MAX;
    #pragma unroll
    for (int kk = 0; kk < 16; ++kk) {
      float acc = base
        + wa.x*h[kk][0]+wa.y*h[kk][1]+wa.z*h[kk][2]+wa.w*h[kk][3]
        + wb.x*h[kk][4]+wb.y*h[kk][5]+wb.z*h[kk][6]+wb.w*h[kk][7];
      float a2 = (acc - mu)*rs*ga + be;
      a2 = a2 >= 0.f ? a2 : 0.2f*a2;
      m = fmaxf(m, a2);
    }
    op[o] = m;
  }
}

// ---------------------------------------------------------------------------
extern "C" void kernel_launch(void* const* d_in, const int* in_sizes, int n_in,
                              void* d_out, int out_size, void* d_ws, size_t ws_size,
                              hipStream_t stream)
{
  (void)in_sizes; (void)n_in; (void)out_size; (void)ws_size;
  const float* x    = (const float*)d_in[0];
  const float* w_in = (const float*)d_in[1];
  const float* b_in = (const float*)d_in[2];
  const float* w1   = (const float*)d_in[3];
  const float* g1   = (const float*)d_in[4];
  const float* be1  = (const float*)d_in[5];
  const float* w2   = (const float*)d_in[6];
  const float* g2   = (const float*)d_in[7];
  const float* be2  = (const float*)d_in[8];
  const float* w3   = (const float*)d_in[9];
  const float* g3   = (const float*)d_in[10];
  const float* be3  = (const float*)d_in[11];
  const float* w4   = (const float*)d_in[12];
  const float* g4   = (const float*)d_in[13];
  const float* be4  = (const float*)d_in[14];

  float* ws = (float*)d_ws;
  float* stats  = ws;                         // 256
  float* f0T    = ws + 256;                   // [8,2048,8]
  int*   idx1   = (int*)(ws + 131328);        // [8,16,2048]
  float* f1T    = ws + 393472;                // [8,2048,32]
  int*   s1     = (int*)(ws + 917760);        // [8,512]
  float* coorq  = ws + 921856;                // [8,3,512]
  int*   idx2   = (int*)(ws + 934144);        // [8,16,512]
  float* f2T    = ws + 999680;                // [8,512,64]
  int*   idx3   = (int*)(ws + 1261824);       // [8,16,512]
  float* f3T    = ws + 1327360;               // [8,512,64]
  int*   s2     = (int*)(ws + 1589504);       // [8,128]
  float* coorq2 = ws + 1590528;               // [8,3,128]
  int*   idx4   = (int*)(ws + 1593600);       // [8,16,128]
  float* ybuf   = ws + 1609984;               // up to [8,64,512,16]

  float* outc = (float*)d_out;                // [8,3,128]
  float* f4   = (float*)d_out + 3072;         // [8,128,128]

  hipMemsetAsync(stats, 0, 256*sizeof(float), stream);

  // FPS(1+2) + input_trans + knn1.
  mega1<<<dim3(4168), 256, 0, stream>>>(
      x, w_in, b_in, f0T, idx1, s1, coorq, s2, coorq2, outc);

  // knn2 + L1 stats + knn3 + knn4.
  mega2<<<dim3(6400), 256, 0, stream>>>(
      f0T, idx1, w1, stats, x, coorq, coorq2, idx2, idx3, idx4);

  // Layer 1 finish.
  l1_pass2<<<64, 256, 0, stream>>>(f0T, idx1, w1, stats, g1, be1, f1T);

  // Layer 2 (C=32 -> O=64, Nq=512, Nk=2048), x_q gathered by s1.
  conv_p1<32, 64, 512, 2048, true><<<dim3(32, 4, 8), 256, 0, stream>>>(
      f1T, 2048, s1, f1T, idx2, w2, ybuf, stats + 64);
  conv_p2<64, 512, true><<<1024, 256, 0, stream>>>(ybuf, stats + 64, g2, be2, f2T);

  // Layer 3 (C=64 -> O=64, Nq=Nk=512).
  conv_p1<64, 64, 512, 512, true><<<dim3(32, 4, 8), 256, 0, stream>>>(
      f2T, 512, nullptr, f2T, idx3, w3, ybuf, stats + 128);
  conv_p2<64, 512, true><<<1024, 256, 0, stream>>>(ybuf, stats + 128, g3, be3, f3T);

  // Layer 4 (C=64 -> O=128, Nq=128, Nk=512), x_q gathered by s2.
  conv_p1<64, 128, 128, 512, true><<<dim3(8, 4, 8), 256, 0, stream>>>(
      f3T, 512, s2, f3T, idx4, w4, ybuf, stats + 192);
  conv_p2<128, 128, false><<<512, 256, 0, stream>>>(ybuf, stats + 192, g4, be4, f4);
}

// Round 8
// 538.016 us; speedup vs baseline: 3.1443x; 1.2403x over previous
//
#include <hip/hip_runtime.h>
#include <float.h>
#include <stdint.h>

// DGCNN_Grouper forward on MI355X. B=8, N=2048, K=16, fp32.
// Round-2 proven architecture (stream-ordered dispatches only). This round:
// two-phase 32-bit DPP argmax/argmin reduces (replacing u64-DPP / shfl
// butterflies) + FPS2 register coord extraction. No device-scope sync.

#define DI __device__ __forceinline__
DI float f_add(float a, float b) { return __fadd_rn(a, b); }
DI float f_sub(float a, float b) { return __fsub_rn(a, b); }
DI float f_mul(float a, float b) { return __fmul_rn(a, b); }

DI uint64_t umax64(uint64_t a, uint64_t b) { return a > b ? a : b; }

// ---------------------------------------------------------------------------
// 32-bit DPP wave reduces (6-step gfx9 pattern validated in r2/r3/r6 for u64).
// Identity via `old` operand: rows/lanes without valid source keep `old`.
// ---------------------------------------------------------------------------
template<int CTRL, int RMASK>
DI uint32_t dpp_umax32(uint32_t v) {
  uint32_t o = (uint32_t)__builtin_amdgcn_update_dpp(0, (int)v, CTRL, RMASK, 0xF, false);
  return v > o ? v : o;
}
template<int CTRL, int RMASK>
DI uint32_t dpp_umin32(uint32_t v) {
  uint32_t o = (uint32_t)__builtin_amdgcn_update_dpp(-1, (int)v, CTRL, RMASK, 0xF, false);
  return v < o ? v : o;
}
template<int CTRL, int RMASK>
DI float dpp_fmin32(float v) {
  int o = __builtin_amdgcn_update_dpp(0x7F7FFFFF /*FLT_MAX*/, __float_as_int(v),
                                      CTRL, RMASK, 0xF, false);
  return fminf(v, __int_as_float(o));
}
DI uint32_t wave_umax_bcast32(uint32_t v) {
  v = dpp_umax32<0x111, 0xF>(v);  // row_shr:1
  v = dpp_umax32<0x112, 0xF>(v);  // row_shr:2
  v = dpp_umax32<0x114, 0xF>(v);  // row_shr:4
  v = dpp_umax32<0x118, 0xF>(v);  // row_shr:8
  v = dpp_umax32<0x142, 0xA>(v);  // row_bcast15
  v = dpp_umax32<0x143, 0xC>(v);  // row_bcast31
  return (uint32_t)__builtin_amdgcn_readlane((int)v, 63);
}
DI uint32_t wave_umin_bcast32(uint32_t v) {
  v = dpp_umin32<0x111, 0xF>(v);
  v = dpp_umin32<0x112, 0xF>(v);
  v = dpp_umin32<0x114, 0xF>(v);
  v = dpp_umin32<0x118, 0xF>(v);
  v = dpp_umin32<0x142, 0xA>(v);
  v = dpp_umin32<0x143, 0xC>(v);
  return (uint32_t)__builtin_amdgcn_readlane((int)v, 63);
}
DI float wave_fmin_bcast32(float v) {
  v = dpp_fmin32<0x111, 0xF>(v);
  v = dpp_fmin32<0x112, 0xF>(v);
  v = dpp_fmin32<0x114, 0xF>(v);
  v = dpp_fmin32<0x118, 0xF>(v);
  v = dpp_fmin32<0x142, 0xA>(v);
  v = dpp_fmin32<0x143, 0xC>(v);
  return __int_as_float(__builtin_amdgcn_readlane(__float_as_int(v), 63));
}

// ---------------------------------------------------------------------------
// kNN: 16 smallest d2, exact reference math ((qq+rr)-2dot can round negative
// => distance phase in f32, index tie-break phase in u32. Selection semantics
// identical to the validated shfl butterfly: min dist, tie -> min index.
// ---------------------------------------------------------------------------
template<int NK>
DI void knn_body(const float* __restrict__ cq, int Nq,
                 const float* __restrict__ ck, int* __restrict__ out,
                 int b, int qbase, float* smem)
{
  constexpr int CPL = NK / 64;
  float* xs = smem;
  float* ys = smem + NK;
  float* zs = smem + 2*NK;
  float* rr = smem + 3*NK;
  const int tid = threadIdx.x;
  for (int i = tid; i < NK; i += 256) {
    float a  = ck[((size_t)b*3 + 0)*NK + i];
    float bb = ck[((size_t)b*3 + 1)*NK + i];
    float c  = ck[((size_t)b*3 + 2)*NK + i];
    xs[i] = a; ys[i] = bb; zs[i] = c;
    rr[i] = f_add(f_add(f_mul(a,a), f_mul(bb,bb)), f_mul(c,c));
  }
  __syncthreads();
  const int lane = tid & 63, w = tid >> 6;
  const int q = qbase + w;
  if (q >= Nq) return;
  float qx = cq[((size_t)b*3 + 0)*Nq + q];
  float qy = cq[((size_t)b*3 + 1)*Nq + q];
  float qz = cq[((size_t)b*3 + 2)*Nq + q];
  float qq = f_add(f_add(f_mul(qx,qx), f_mul(qy,qy)), f_mul(qz,qz));
  float v[CPL];
  #pragma unroll
  for (int j = 0; j < CPL; ++j) {
    int c = j*64 + lane;
    float dot = f_add(f_add(f_mul(qx,xs[c]), f_mul(qy,ys[c])), f_mul(qz,zs[c]));
    v[j] = f_sub(f_add(qq, rr[c]), f_mul(2.0f, dot));
  }
  unsigned mask = (CPL >= 32) ? 0xFFFFFFFFu : ((1u << CPL) - 1u);
  for (int r = 0; r < 16; ++r) {
    float bv = FLT_MAX; int bc = 0x7FFFFFFF;
    #pragma unroll
    for (int j = 0; j < CPL; ++j) {
      float vj = ((mask >> j) & 1u) ? v[j] : FLT_MAX;
      if (vj < bv) { bv = vj; bc = j*64 + lane; }   // j asc => idx asc, first wins
    }
    float wmin = wave_fmin_bcast32(bv);
    uint32_t cand = (bv == wmin) ? (uint32_t)bc : 0xFFFFFFFFu;
    uint32_t wbc = wave_umin_bcast32(cand);
    if ((wbc & 63) == (uint32_t)lane) mask &= ~(1u << (wbc >> 6));
    if (lane == 0) out[((size_t)b*16 + r)*Nq + q] = (int)wbc;
  }
}

// ---------------------------------------------------------------------------
// FPS (round-2 proven structure; two-phase u32 reduce; FPS distances are sums
// of squares >= +0 so u32 order == f32 order). Level 1: 4 waves, lane-0 slot
// write + barrier + pts[far] read. Level 2: single wave, coords via uniform
// register select + readlane (no LDS dependency in the loop).
// ---------------------------------------------------------------------------
__device__ void fps_body(const float* __restrict__ x, int b,
                         int* __restrict__ s1, float* __restrict__ coorq,
                         int* __restrict__ s2, float* __restrict__ coorq2,
                         float* __restrict__ outc, char* smem_raw)
{
  float4*   pts  = (float4*)smem_raw;                       // [2048]
  int*      sel  = (int*)(smem_raw + 32768);                // [512]
  uint64_t* wkey = (uint64_t*)(smem_raw + 32768 + 2048);    // [8] (2 parity x 4 waves)
  const int tid = threadIdx.x, lane = tid & 63, w = tid >> 6;

  for (int i = tid; i < 2048; i += 256)
    pts[i] = make_float4(x[((size_t)b*3 + 0)*2048 + i],
                         x[((size_t)b*3 + 1)*2048 + i],
                         x[((size_t)b*3 + 2)*2048 + i], 0.f);
  __syncthreads();

  float px[8], py[8], pz[8], dl[8];
  #pragma unroll
  for (int j = 0; j < 8; ++j) {
    float4 p = pts[tid + 256*j];
    px[j] = p.x; py[j] = p.y; pz[j] = p.z; dl[j] = 1e10f;
  }

  int far = 0;
  float4 c = pts[0];
  for (int i = 0; i < 512; ++i) {
    if (tid == 0) sel[i] = far;
    float bd = -1.0f; uint32_t bi = 0;
    #pragma unroll
    for (int j = 0; j < 8; ++j) {
      float dx = f_sub(px[j], c.x);
      float dy = f_sub(py[j], c.y);
      float dz = f_sub(pz[j], c.z);
      float d  = f_add(f_add(f_mul(dx,dx), f_mul(dy,dy)), f_mul(dz,dz));
      float nd = fminf(dl[j], d);
      dl[j] = nd;
      if (nd > bd) { bd = nd; bi = (uint32_t)(tid + 256*j); }  // strict >: first max wins
    }
    uint32_t db = __float_as_uint(bd);              // bd >= +0 always
    uint32_t wd = wave_umax_bcast32(db);
    uint32_t cand = (db == wd) ? bi : 0xFFFFFFFFu;
    uint32_t wi = wave_umin_bcast32(cand);
    if (lane == 0) wkey[(i & 1)*4 + w] = ((uint64_t)wd << 32) | (uint32_t)~wi;
    __syncthreads();
    const uint64_t* wk = wkey + (i & 1)*4;
    uint64_t g = umax64(umax64(wk[0], wk[1]), umax64(wk[2], wk[3]));
    far = (int)~(uint32_t)g;
    c = pts[far];
  }
  __syncthreads();

  // Dump level 1; bounce selected points into pts[0..511].
  int p0 = sel[tid], p1 = sel[tid + 256];
  float4 v0 = pts[p0], v1 = pts[p1];
  s1[b*512 + tid]       = p0;
  s1[b*512 + tid + 256] = p1;
  coorq[((size_t)b*3 + 0)*512 + tid] = v0.x;
  coorq[((size_t)b*3 + 1)*512 + tid] = v0.y;
  coorq[((size_t)b*3 + 2)*512 + tid] = v0.z;
  coorq[((size_t)b*3 + 0)*512 + tid + 256] = v1.x;
  coorq[((size_t)b*3 + 1)*512 + tid + 256] = v1.y;
  coorq[((size_t)b*3 + 2)*512 + tid + 256] = v1.z;
  __syncthreads();               // all pts reads complete before overwrite
  pts[tid] = v0; pts[tid + 256] = v1;
  __syncthreads();

  // Level 2: 512 -> 128, single wave, no LDS dependency inside the loop.
  if (w == 0) {
    float qx[8], qy[8], qz[8], d2[8];
    #pragma unroll
    for (int j = 0; j < 8; ++j) {
      float4 p = pts[lane + 64*j];
      qx[j] = p.x; qy[j] = p.y; qz[j] = p.z; d2[j] = 1e10f;
    }
    int far2 = 0;
    float cx = pts[0].x, cy = pts[0].y, cz = pts[0].z;
    for (int i = 0; i < 128; ++i) {
      if (lane == 0) sel[i] = far2;
      float bd = -1.0f; uint32_t bi = 0;
      #pragma unroll
      for (int j = 0; j < 8; ++j) {
        float dx = f_sub(qx[j], cx);
        float dy = f_sub(qy[j], cy);
        float dz = f_sub(qz[j], cz);
        float d  = f_add(f_add(f_mul(dx,dx), f_mul(dy,dy)), f_mul(dz,dz));
        float nd = fminf(d2[j], d);
        d2[j] = nd;
        if (nd > bd) { bd = nd; bi = (uint32_t)(lane + 64*j); }
      }
      uint32_t db = __float_as_uint(bd);
      uint32_t wd = wave_umax_bcast32(db);
      uint32_t cand = (db == wd) ? bi : 0xFFFFFFFFu;
      uint32_t wi = wave_umin_bcast32(cand);
      far2 = (int)wi;
      // winner coords from registers: uniform 8-way select + readlane
      uint32_t js = wi >> 6, ls = wi & 63;
      float sx = qx[0], sy = qy[0], sz = qz[0];
      #pragma unroll
      for (uint32_t t = 1; t < 8; ++t) {
        sx = (js == t) ? qx[t] : sx;
        sy = (js == t) ? qy[t] : sy;
        sz = (js == t) ? qz[t] : sz;
      }
      cx = __int_as_float(__builtin_amdgcn_readlane(__float_as_int(sx), ls));
      cy = __int_as_float(__builtin_amdgcn_readlane(__float_as_int(sy), ls));
      cz = __int_as_float(__builtin_amdgcn_readlane(__float_as_int(sz), ls));
    }
  }
  __syncthreads();
  if (tid < 128) {
    int p = sel[tid];
    float4 v = pts[p];
    s2[b*128 + tid] = p;
    coorq2[((size_t)b*3 + 0)*128 + tid] = v.x;
    coorq2[((size_t)b*3 + 1)*128 + tid] = v.y;
    coorq2[((size_t)b*3 + 2)*128 + tid] = v.z;
    outc[((size_t)b*3 + 0)*128 + tid] = v.x;
    outc[((size_t)b*3 + 1)*128 + tid] = v.y;
    outc[((size_t)b*3 + 2)*128 + tid] = v.z;
  }
}

// ---------------------------------------------------------------------------
// mega1: blocks 0-7 FPS, 8-71 input_trans, 72+ knn1. Mutually independent.
// ---------------------------------------------------------------------------
__global__ __launch_bounds__(256) void mega1(
    const float* __restrict__ x, const float* __restrict__ w_in, const float* __restrict__ b_in,
    float* __restrict__ f0T, int* __restrict__ idx1,
    int* __restrict__ s1, float* __restrict__ coorq,
    int* __restrict__ s2, float* __restrict__ coorq2, float* __restrict__ outc)
{
  __shared__ char smem_raw[35008] __attribute__((aligned(16)));
  const int bid = blockIdx.x;
  if (bid < 8) {
    fps_body(x, bid, s1, coorq, s2, coorq2, outc, smem_raw);
  } else if (bid < 72) {
    int t = (bid - 8)*256 + threadIdx.x;
    int b = t >> 11, n = t & 2047;
    float x0 = x[((size_t)b*3 + 0)*2048 + n];
    float x1 = x[((size_t)b*3 + 1)*2048 + n];
    float x2 = x[((size_t)b*3 + 2)*2048 + n];
    float* op = f0T + (size_t)t*8;
    #pragma unroll
    for (int o = 0; o < 8; ++o)
      op[o] = w_in[o*3+0]*x0 + w_in[o*3+1]*x1 + w_in[o*3+2]*x2 + b_in[o];
  } else {
    int vb = bid - 72;
    int b = vb >> 9;
    int qbase = (vb & 511)*4;
    knn_body<2048>(x, 2048, x, idx1, b, qbase, (float*)smem_raw);
  }
}

// ---------------------------------------------------------------------------
// Edge conv pass1 body (round-2 verbatim).
// ---------------------------------------------------------------------------
template<int C, int O, int NQ, int NK, bool STORE>
DI void conv_p1_body(
    const float* __restrict__ xqT, int xq_cols, const int* __restrict__ qg,
    const float* __restrict__ xkT, const int* __restrict__ knn_idx,
    const float* __restrict__ w, float* __restrict__ y, float* __restrict__ stats,
    int nt, int g, int b, float* smem)
{
  constexpr int GRP = O/4;
  const int tid = threadIdx.x;
  float* sxq = smem;
  float* sw  = smem + 16*C;
  float* red = sw + GRP*2*C;
  for (int i = tid; i < 16*C; i += 256) {
    int nn = i / C, ci = i % C;
    int q = nt*16 + nn;
    int src = qg ? qg[b*NQ + q] : q;
    sxq[i] = xqT[((size_t)b*xq_cols + src)*C + ci];
  }
  for (int i = tid; i < GRP*2*C; i += 256)
    sw[i] = w[(size_t)g*GRP*2*C + i];
  __syncthreads();

  const int nloc = tid >> 4, kk = tid & 15;
  const int n = nt*16 + nloc;
  const int flat = n*16 + kk;
  const int r = flat / NQ, s = flat % NQ;
  const int nbr = knn_idx[((size_t)b*16 + r)*NQ + s];

  float xqv[C], h1[C];
  {
    const float4* xq4 = (const float4*)(sxq + nloc*C);
    const float4* xk4 = (const float4*)(xkT + ((size_t)b*NK + nbr)*C);
    #pragma unroll
    for (int c4 = 0; c4 < C/4; ++c4) {
      float4 a = xq4[c4], k = xk4[c4];
      xqv[4*c4+0] = a.x; xqv[4*c4+1] = a.y; xqv[4*c4+2] = a.z; xqv[4*c4+3] = a.w;
      h1[4*c4+0] = k.x - a.x; h1[4*c4+1] = k.y - a.y;
      h1[4*c4+2] = k.z - a.z; h1[4*c4+3] = k.w - a.w;
    }
  }
  float lsum = 0.f, lsq = 0.f;
  float* yp = nullptr;
  if constexpr (STORE) yp = y + (((size_t)b*O + (size_t)g*GRP)*NQ + n)*16 + kk;
  for (int o = 0; o < GRP; ++o) {
    const float4* wr = (const float4*)(sw + o*2*C);
    float acc = 0.f;
    #pragma unroll
    for (int c4 = 0; c4 < C/4; ++c4) {
      float4 w4 = wr[c4];
      acc += w4.x*h1[4*c4] + w4.y*h1[4*c4+1] + w4.z*h1[4*c4+2] + w4.w*h1[4*c4+3];
    }
    #pragma unroll
    for (int c4 = 0; c4 < C/4; ++c4) {
      float4 w4 = wr[C/4 + c4];
      acc += w4.x*xqv[4*c4] + w4.y*xqv[4*c4+1] + w4.z*xqv[4*c4+2] + w4.w*xqv[4*c4+3];
    }
    if constexpr (STORE) yp[(size_t)o*NQ*16] = acc;
    lsum += acc; lsq += acc*acc;
  }
  #pragma unroll
  for (int off = 32; off; off >>= 1) {
    lsum += __shfl_xor(lsum, off);
    lsq  += __shfl_xor(lsq, off);
  }
  const int lane = tid & 63, wvid = tid >> 6;
  if (lane == 0) { red[wvid] = lsum; red[4+wvid] = lsq; }
  __syncthreads();
  if (tid == 0) {
    float s0  = (red[0]+red[1]) + (red[2]+red[3]);
    float s1v = (red[4]+red[5]) + (red[6]+red[7]);
    atomicAdd(stats + ((size_t)b*4 + g)*2,     s0);
    atomicAdd(stats + ((size_t)b*4 + g)*2 + 1, s1v);
  }
}

template<int C, int O, int NQ, int NK, bool STORE>
__global__ __launch_bounds__(256) void conv_p1(
    const float* __restrict__ xqT, int xq_cols, const int* __restrict__ qg,
    const float* __restrict__ xkT, const int* __restrict__ knn_idx,
    const float* __restrict__ w, float* __restrict__ y, float* __restrict__ stats)
{
  __shared__ float smem_f[16*C + (O/4)*2*C + 8];
  conv_p1_body<C, O, NQ, NK, STORE>(xqT, xq_cols, qg, xkT, knn_idx, w, y, stats,
                                    blockIdx.x, blockIdx.y, blockIdx.z, smem_f);
}

// ---------------------------------------------------------------------------
// mega2: knn2 + conv_p1(L1 stats) + knn3 + knn4 in one dispatch.
// ---------------------------------------------------------------------------
__global__ __launch_bounds__(256) void mega2(
    const float* __restrict__ f0T, const int* __restrict__ idx1,
    const float* __restrict__ w1, float* __restrict__ stats,
    const float* __restrict__ x, const float* __restrict__ coorq,
    const float* __restrict__ coorq2,
    int* __restrict__ idx2, int* __restrict__ idx3, int* __restrict__ idx4)
{
  __shared__ char smem_raw[32768] __attribute__((aligned(16)));
  const int bid = blockIdx.x;
  if (bid < 1024) {
    knn_body<2048>(coorq, 512, x, idx2, bid >> 7, (bid & 127)*4, (float*)smem_raw);
  } else if (bid < 5120) {
    int f = bid - 1024;
    conv_p1_body<8, 32, 2048, 2048, false>(f0T, 2048, nullptr, f0T, idx1, w1,
                                           nullptr, stats,
                                           f & 127, (f >> 7) & 3, f >> 9,
                                           (float*)smem_raw);
  } else if (bid < 6144) {
    int v = bid - 5120;
    knn_body<512>(coorq, 512, coorq, idx3, v >> 7, (v & 127)*4, (float*)smem_raw);
  } else {
    int v = bid - 6144;
    knn_body<512>(coorq2, 128, coorq, idx4, v >> 5, (v & 31)*4, (float*)smem_raw);
  }
}

// pass2 for layers 2-4.
template<int O, int NQ, bool TOUT>
__global__ __launch_bounds__(256) void conv_p2(
    const float* __restrict__ y, const float* __restrict__ stats,
    const float* __restrict__ gamma, const float* __restrict__ beta,
    float* __restrict__ fout)
{
  int t = blockIdx.x*256 + threadIdx.x;
  if (t >= 8*O*NQ) return;
  int b = t / (O*NQ);
  int rem = t % (O*NQ);
  int o, n;
  if (TOUT) { o = rem % O; n = rem / O; }
  else      { n = rem % NQ; o = rem / NQ; }
  int g = o / (O/4);
  const float cnt = (float)((O/4) * NQ * 16);
  float s0 = stats[((size_t)b*4 + g)*2], s1v = stats[((size_t)b*4 + g)*2 + 1];
  float mu = s0 / cnt;
  float var = fmaxf(s1v / cnt - mu*mu, 0.f);
  float rs = 1.f / sqrtf(var + 1e-5f);
  float ga = gamma[o], be = beta[o];
  const float4* yp = (const float4*)(y + ((((size_t)b*O + o)*NQ) + n)*16);
  float m = -FLT_MAX;
  #pragma unroll
  for (int i = 0; i < 4; ++i) {
    float4 v4 = yp[i];
    float vv[4] = {v4.x, v4.y, v4.z, v4.w};
    #pragma unroll
    for (int j = 0; j < 4; ++j) {
      float a = (vv[j] - mu)*rs*ga + be;
      a = a >= 0.f ? a : 0.2f*a;
      m = fmaxf(m, a);
    }
  }
  fout[t] = m;
}

// Layer-1 pass2: recompute conv + GN + lrelu + max.
__global__ __launch_bounds__(256) void l1_pass2(
    const float* __restrict__ f0T, const int* __restrict__ idx1,
    const float* __restrict__ w1, const float* __restrict__ stats,
    const float* __restrict__ g1, const float* __restrict__ be1,
    float* __restrict__ f1T)
{
  alignas(16) __shared__ float sw[512];
  __shared__ float sg[32], sb[32];
  int tid = threadIdx.x;
  for (int i = tid; i < 512; i += 256) sw[i] = w1[i];
  if (tid < 32) { sg[tid] = g1[tid]; sb[tid] = be1[tid]; }
  __syncthreads();
  int t = blockIdx.x*256 + tid;
  int b = t >> 11, n = t & 2047;
  float mean[4], rstd[4];
  const float cnt = 8.f*2048.f*16.f;
  #pragma unroll
  for (int g = 0; g < 4; ++g) {
    float mu = stats[(b*4+g)*2] / cnt;
    float var = fmaxf(stats[(b*4+g)*2+1]/cnt - mu*mu, 0.f);
    mean[g] = mu; rstd[g] = 1.f/sqrtf(var + 1e-5f);
  }
  const float4* xqp = (const float4*)(f0T + (size_t)t*8);
  float4 q0 = xqp[0], q1 = xqp[1];
  float xq[8] = {q0.x,q0.y,q0.z,q0.w,q1.x,q1.y,q1.z,q1.w};
  float h[16][8];
  #pragma unroll
  for (int kk = 0; kk < 16; ++kk) {
    int flat = n*16 + kk, r = flat >> 11, s = flat & 2047;
    int nbr = idx1[((b*16 + r) << 11) + s];
    const float4* xkp = (const float4*)(f0T + ((size_t)(b << 11) + nbr)*8);
    float4 k0 = xkp[0], k1 = xkp[1];
    h[kk][0]=k0.x-xq[0]; h[kk][1]=k0.y-xq[1]; h[kk][2]=k0.z-xq[2]; h[kk][3]=k0.w-xq[3];
    h[kk][4]=k1.x-xq[4]; h[kk][5]=k1.y-xq[5]; h[kk][6]=k1.z-xq[6]; h[kk][7]=k1.w-xq[7];
  }
  float* op = f1T + (size_t)t*32;
  for (int o = 0; o < 32; ++o) {
    const float4* wp4 = (const float4*)(sw + o*16);
    float4 wa = wp4[0], wb = wp4[1], wc = wp4[2], wd = wp4[3];
    float base = wc.x*xq[0]+wc.y*xq[1]+wc.z*xq[2]+wc.w*xq[3]
               + wd.x*xq[4]+wd.y*xq[5]+wd.z*xq[6]+wd.w*xq[7];
    int g = o >> 3;
    float mu = mean[g], rs = rstd[g], ga = sg[o], be = sb[o];
    float m = -FLT_MAX;
    #pragma unroll
    for (int kk = 0; kk < 16; ++kk) {
      float acc = base
        + wa.x*h[kk][0]+wa.y*h[kk][1]+wa.z*h[kk][2]+wa.w*h[kk][3]
        + wb.x*h[kk][4]+wb.y*h[kk][5]+wb.z*h[kk][6]+wb.w*h[kk][7];
      float a2 = (acc - mu)*rs*ga + be;
      a2 = a2 >= 0.f ? a2 : 0.2f*a2;
      m = fmaxf(m, a2);
    }
    op[o] = m;
  }
}

// ---------------------------------------------------------------------------
extern "C" void kernel_launch(void* const* d_in, const int* in_sizes, int n_in,
                              void* d_out, int out_size, void* d_ws, size_t ws_size,
                              hipStream_t stream)
{
  (void)in_sizes; (void)n_in; (void)out_size; (void)ws_size;
  const float* x    = (const float*)d_in[0];
  const float* w_in = (const float*)d_in[1];
  const float* b_in = (const float*)d_in[2];
  const float* w1   = (const float*)d_in[3];
  const float* g1   = (const float*)d_in[4];
  const float* be1  = (const float*)d_in[5];
  const float* w2   = (const float*)d_in[6];
  const float* g2   = (const float*)d_in[7];
  const float* be2  = (const float*)d_in[8];
  const float* w3   = (const float*)d_in[9];
  const float* g3   = (const float*)d_in[10];
  const float* be3  = (const float*)d_in[11];
  const float* w4   = (const float*)d_in[12];
  const float* g4   = (const float*)d_in[13];
  const float* be4  = (const float*)d_in[14];

  float* ws = (float*)d_ws;
  float* stats  = ws;                         // 256
  float* f0T    = ws + 256;                   // [8,2048,8]
  int*   idx1   = (int*)(ws + 131328);        // [8,16,2048]
  float* f1T    = ws + 393472;                // [8,2048,32]
  int*   s1     = (int*)(ws + 917760);        // [8,512]
  float* coorq  = ws + 921856;                // [8,3,512]
  int*   idx2   = (int*)(ws + 934144);        // [8,16,512]
  float* f2T    = ws + 999680;                // [8,512,64]
  int*   idx3   = (int*)(ws + 1261824);       // [8,16,512]
  float* f3T    = ws + 1327360;               // [8,512,64]
  int*   s2     = (int*)(ws + 1589504);       // [8,128]
  float* coorq2 = ws + 1590528;               // [8,3,128]
  int*   idx4   = (int*)(ws + 1593600);       // [8,16,128]
  float* ybuf   = ws + 1609984;               // up to [8,64,512,16]

  float* outc = (float*)d_out;                // [8,3,128]
  float* f4   = (float*)d_out + 3072;         // [8,128,128]

  hipMemsetAsync(stats, 0, 256*sizeof(float), stream);

  // FPS(1+2) + input_trans + knn1.
  mega1<<<dim3(4168), 256, 0, stream>>>(
      x, w_in, b_in, f0T, idx1, s1, coorq, s2, coorq2, outc);

  // knn2 + L1 stats + knn3 + knn4.
  mega2<<<dim3(6400), 256, 0, stream>>>(
      f0T, idx1, w1, stats, x, coorq, coorq2, idx2, idx3, idx4);

  // Layer 1 finish.
  l1_pass2<<<64, 256, 0, stream>>>(f0T, idx1, w1, stats, g1, be1, f1T);

  // Layer 2 (C=32 -> O=64, Nq=512, Nk=2048), x_q gathered by s1.
  conv_p1<32, 64, 512, 2048, true><<<dim3(32, 4, 8), 256, 0, stream>>>(
      f1T, 2048, s1, f1T, idx2, w2, ybuf, stats + 64);
  conv_p2<64, 512, true><<<1024, 256, 0, stream>>>(ybuf, stats + 64, g2, be2, f2T);

  // Layer 3 (C=64 -> O=64, Nq=Nk=512).
  conv_p1<64, 64, 512, 512, true><<<dim3(32, 4, 8), 256, 0, stream>>>(
      f2T, 512, nullptr, f2T, idx3, w3, ybuf, stats + 128);
  conv_p2<64, 512, true><<<1024, 256, 0, stream>>>(ybuf, stats + 128, g3, be3, f3T);

  // Layer 4 (C=64 -> O=128, Nq=128, Nk=512), x_q gathered by s2.
  conv_p1<64, 128, 128, 512, true><<<dim3(8, 4, 8), 256, 0, stream>>>(
      f3T, 512, s2, f3T, idx4, w4, ybuf, stats + 192);
  conv_p2<128, 128, false><<<512, 256, 0, stream>>>(ybuf, stats + 192, g4, be4, f4);
}